// Round 1
// baseline (112.623 us; speedup 1.0000x reference)
//
#include <hip/hip_runtime.h>
#include <math.h>

// Problem constants (from the reference):
//  levels: (64,64,s=8,bs=32) (32,32,s=16,bs=64) (16,16,s=32,bs=128) (8,8,s=64,bs=256)
//  K = 9 anchors/position (3 ratios x 3 scales), A = 48960, B = 16, M = 64 GT boxes
#define A_TOTAL 48960
#define M_GT    64
#define B_BATCH 16

__global__ __launch_bounds__(256) void anchors_assign_kernel(
    const float* __restrict__ gt_boxes,   // (B, 64, 4) xyxy
    const int*   __restrict__ gt_labels,  // (B, 64)
    float* __restrict__ out_loc,          // (B, A, 4)
    float* __restrict__ out_cls)          // (B, A)
{
    __shared__ float4 sbox[M_GT];
    __shared__ float  sarea[M_GT];
    __shared__ float  slab[M_GT];

    const int b   = blockIdx.y;
    const int tid = threadIdx.x;

    // Stage this batch's GT boxes into LDS (64 x float4 = 1 KiB)
    if (tid < M_GT) {
        float4 g = ((const float4*)gt_boxes)[b * M_GT + tid];
        sbox[tid]  = g;
        sarea[tid] = (g.z - g.x) * (g.w - g.y);   // area_g, same op order as ref
        slab[tid]  = (float)gt_labels[b * M_GT + tid];
    }
    __syncthreads();

    const int a = blockIdx.x * 256 + tid;
    if (a >= A_TOTAL) return;

    // ---- decode anchor index -> level, position, k ----
    int local, W, stride, bs;
    if (a < 36864)      { local = a;         W = 64; stride = 8;  bs = 32;  }
    else if (a < 46080) { local = a - 36864; W = 32; stride = 16; bs = 64;  }
    else if (a < 48384) { local = a - 46080; W = 16; stride = 32; bs = 128; }
    else                { local = a - 48384; W = 8;  stride = 64; bs = 256; }

    const int hw = local / 9;          // magic-mul division
    const int k  = local - hw * 9;
    const int y  = hw / W;             // W is power of two -> shift
    const int x  = hw - y * W;
    const int r  = k / 3;              // ratio index
    const int s  = k - r * 3;          // scale index

    // ---- anchor w/h in double, exactly mirroring numpy's op order ----
    // a = bs*scale; area = a*a; w = sqrt(area*rr); h = w/rr; cast f32
    const double sc = (s == 0) ? 1.0 : ((s == 1) ? 1.2599210498948732   // 2^(1/3)
                                                 : 1.5874010519681994); // 2^(2/3)
    const double rr = (r == 0) ? 0.5 : ((r == 1) ? 1.0 : 2.0);
    const double av   = (double)bs * sc;
    const double area = av * av;
    const double wd   = sqrt(area * rr);
    const double hd   = wd / rr;
    const float aw = (float)wd, ah = (float)hd;

    const float acx = ((float)x + 0.5f) * (float)stride;
    const float acy = ((float)y + 0.5f) * (float)stride;
    const float hx = aw * 0.5f, hy = ah * 0.5f;
    const float ax1 = acx - hx, ay1 = acy - hy;
    const float ax2 = acx + hx, ay2 = acy + hy;
    const float areaA = (ax2 - ax1) * (ay2 - ay1);   // ref recomputes from xyxy

    // ---- IoU max/argmax over 64 GT boxes (strict > keeps first index, as np.argmax) ----
    float best = -1.0f;
    int   bidx = 0;
    #pragma unroll 8
    for (int j = 0; j < M_GT; ++j) {
        const float4 g = sbox[j];                    // wave-uniform -> LDS broadcast
        const float ltx = fmaxf(ax1, g.x), lty = fmaxf(ay1, g.y);
        const float rbx = fminf(ax2, g.z), rby = fminf(ay2, g.w);
        const float wx = fmaxf(rbx - ltx, 0.0f);
        const float wy = fmaxf(rby - lty, 0.0f);
        const float inter = wx * wy;
        const float iou = inter / (areaA + sarea[j] - inter);
        if (iou > best) { best = iou; bidx = j; }
    }

    // ---- label thresholding (order matches ref: ign first, bg overrides) ----
    float lab = slab[bidx];
    if (best > 0.4f && best < 0.5f) lab = -1.0f;
    if (best < 0.4f)                lab = 0.0f;

    // ---- box deltas from the argmax box ----
    const float4 g = sbox[bidx];
    const float gcx = (g.x + g.z) * 0.5f;
    const float gcy = (g.y + g.w) * 0.5f;
    const float tx = (gcx - acx) / (aw * 0.1f);
    const float ty = (gcy - acy) / (ah * 0.1f);
    const float tw = logf((g.z - g.x) / aw) / 0.2f;
    const float th = logf((g.w - g.y) / ah) / 0.2f;

    const size_t idx = (size_t)b * A_TOTAL + a;
    ((float4*)out_loc)[idx] = make_float4(tx, ty, tw, th);  // coalesced 16B store
    out_cls[idx] = lab;
}

extern "C" void kernel_launch(void* const* d_in, const int* in_sizes, int n_in,
                              void* d_out, int out_size, void* d_ws, size_t ws_size,
                              hipStream_t stream) {
    // inputs: f3, f4, f5, f6 (unused data, shapes are compile-time constants),
    //         gt_boxes (B,64,4) f32, gt_labels (B,64) int
    const float* gt_boxes  = (const float*)d_in[4];
    const int*   gt_labels = (const int*)d_in[5];

    float* out_loc = (float*)d_out;                                  // (B, A, 4)
    float* out_cls = (float*)d_out + (size_t)B_BATCH * A_TOTAL * 4;  // (B, A)

    dim3 grid((A_TOTAL + 255) / 256, B_BATCH);   // 192 x 16 blocks
    anchors_assign_kernel<<<grid, 256, 0, stream>>>(gt_boxes, gt_labels, out_loc, out_cls);
}

// Round 2
// 102.389 us; speedup vs baseline: 1.1000x; 1.1000x over previous
//
#include <hip/hip_runtime.h>
#include <math.h>

// Problem constants (from the reference):
//  levels: (64,64,s=8,bs=32) (32,32,s=16,bs=64) (16,16,s=32,bs=128) (8,8,s=64,bs=256)
//  K = 9 anchors/position (3 ratios x 3 scales), A = 48960, B = 16, M = 64 GT boxes
#define A_TOTAL 48960
#define M_GT    64
#define B_BATCH 16

__global__ __launch_bounds__(256) void anchors_assign_kernel(
    const float* __restrict__ gt_boxes,   // (B, 64, 4) xyxy
    const int*   __restrict__ gt_labels,  // (B, 64)
    float* __restrict__ out_loc,          // (B, A, 4)
    float* __restrict__ out_cls)          // (B, A)
{
    __shared__ float4 sbox[M_GT];
    __shared__ float  sarea[M_GT];
    __shared__ float  slab[M_GT];

    const int b   = blockIdx.y;
    const int tid = threadIdx.x;

    // Stage this batch's GT boxes into LDS (64 x float4 = 1 KiB)
    if (tid < M_GT) {
        float4 g = ((const float4*)gt_boxes)[b * M_GT + tid];
        sbox[tid]  = g;
        sarea[tid] = (g.z - g.x) * (g.w - g.y);   // area_g, same op order as ref
        slab[tid]  = (float)gt_labels[b * M_GT + tid];
    }
    __syncthreads();

    const int a = blockIdx.x * 256 + tid;
    if (a >= A_TOTAL) return;

    // ---- decode anchor index -> level, position, k ----
    int local, W, stride, bs;
    if (a < 36864)      { local = a;         W = 64; stride = 8;  bs = 32;  }
    else if (a < 46080) { local = a - 36864; W = 32; stride = 16; bs = 64;  }
    else if (a < 48384) { local = a - 46080; W = 16; stride = 32; bs = 128; }
    else                { local = a - 48384; W = 8;  stride = 64; bs = 256; }

    const int hw = local / 9;          // magic-mul division
    const int k  = local - hw * 9;
    const int y  = hw / W;             // W is power of two -> shift
    const int x  = hw - y * W;
    const int r  = k / 3;              // ratio index
    const int s  = k - r * 3;          // scale index

    // ---- anchor w/h in double, exactly mirroring numpy's op order ----
    // a = bs*scale; area = a*a; w = sqrt(area*rr); h = w/rr; cast f32
    const double sc = (s == 0) ? 1.0 : ((s == 1) ? 1.2599210498948732   // 2^(1/3)
                                                 : 1.5874010519681994); // 2^(2/3)
    const double rr = (r == 0) ? 0.5 : ((r == 1) ? 1.0 : 2.0);
    const double av   = (double)bs * sc;
    const double area = av * av;
    const double wd   = sqrt(area * rr);
    const double hd   = wd / rr;
    const float aw = (float)wd, ah = (float)hd;

    const float acx = ((float)x + 0.5f) * (float)stride;
    const float acy = ((float)y + 0.5f) * (float)stride;
    const float hx = aw * 0.5f, hy = ah * 0.5f;
    const float ax1 = acx - hx, ay1 = acy - hy;
    const float ax2 = acx + hx, ay2 = acy + hy;
    const float areaA = (ax2 - ax1) * (ay2 - ay1);   // ref recomputes from xyxy

    // ---- IoU argmax over 64 GT boxes, division-free ----
    // All denominators > 0, so iou_j > iou_best  <=>  inter_j*den_best > inter_best*den_j.
    // Products bounded by ~2e9 -> no fp32 overflow. Strict '>' keeps the first max,
    // matching np.argmax. Init (b_inter=-1, b_den=1) makes j=0 always win:
    // inter_0*1 > -1*den_0 since den_0 > 0.
    float b_inter = -1.0f, b_den = 1.0f;
    int   bidx = 0;
    #pragma unroll 16
    for (int j = 0; j < M_GT; ++j) {
        const float4 g = sbox[j];                    // wave-uniform -> LDS broadcast
        const float ltx = fmaxf(ax1, g.x), lty = fmaxf(ay1, g.y);
        const float rbx = fminf(ax2, g.z), rby = fminf(ay2, g.w);
        const float wx = fmaxf(rbx - ltx, 0.0f);
        const float wy = fmaxf(rby - lty, 0.0f);
        const float inter = wx * wy;
        const float den   = (areaA + sarea[j]) - inter;   // same assoc as ref
        if (inter * b_den > b_inter * den) {
            b_inter = inter; b_den = den; bidx = j;
        }
    }
    // One exact IEEE divide: bit-identical to the ref's iou for the winning j,
    // so the 0.4/0.5 threshold tests agree whenever the argmax agrees.
    const float best = b_inter / b_den;

    // ---- label thresholding (order matches ref: ign first, bg overrides) ----
    float lab = slab[bidx];
    if (best > 0.4f && best < 0.5f) lab = -1.0f;
    if (best < 0.4f)                lab = 0.0f;

    // ---- box deltas from the argmax box ----
    const float4 g = sbox[bidx];
    const float gcx = (g.x + g.z) * 0.5f;
    const float gcy = (g.y + g.w) * 0.5f;
    const float tx = (gcx - acx) / (aw * 0.1f);
    const float ty = (gcy - acy) / (ah * 0.1f);
    const float tw = __logf((g.z - g.x) / aw) * 5.0f;   // /0.2 ; approx log, tol ~4
    const float th = __logf((g.w - g.y) / ah) * 5.0f;

    const size_t idx = (size_t)b * A_TOTAL + a;
    ((float4*)out_loc)[idx] = make_float4(tx, ty, tw, th);  // coalesced 16B store
    out_cls[idx] = lab;
}

extern "C" void kernel_launch(void* const* d_in, const int* in_sizes, int n_in,
                              void* d_out, int out_size, void* d_ws, size_t ws_size,
                              hipStream_t stream) {
    // inputs: f3, f4, f5, f6 (unused data, shapes are compile-time constants),
    //         gt_boxes (B,64,4) f32, gt_labels (B,64) int
    const float* gt_boxes  = (const float*)d_in[4];
    const int*   gt_labels = (const int*)d_in[5];

    float* out_loc = (float*)d_out;                                  // (B, A, 4)
    float* out_cls = (float*)d_out + (size_t)B_BATCH * A_TOTAL * 4;  // (B, A)

    dim3 grid((A_TOTAL + 255) / 256, B_BATCH);   // 192 x 16 blocks
    anchors_assign_kernel<<<grid, 256, 0, stream>>>(gt_boxes, gt_labels, out_loc, out_cls);
}